// Round 1
// baseline (479.970 us; speedup 1.0000x reference)
//
#include <hip/hip_runtime.h>
#include <math.h>

#define NB 4
#define NP 4096   // src points per batch
#define MP 4096   // tgt points per batch

// ---------------------------------------------------------------------------
// Workspace layout (floats):
//   tgt4     : [0,      65536)   NB*MP float4 (x,y,z,|t|^2)
//   S        : [65536, 114688)   NB*NP*3 current transformed src
//   partials : [114688,131072)   1024 rows x 16 floats (256 blocks x 4 waves)
//   Rt       : [131072,131120)   R[4][3][3] flat (36) + t[4][3] flat (12)
// ---------------------------------------------------------------------------

__global__ __launch_bounds__(256) void init_tgt(const float* __restrict__ tgt,
                                                float4* __restrict__ tgt4) {
    int j = blockIdx.x * 256 + threadIdx.x;       // 0..16383
    float x = tgt[j * 3 + 0];
    float y = tgt[j * 3 + 1];
    float z = tgt[j * 3 + 2];
    tgt4[j] = make_float4(x, y, z, x * x + y * y + z * z);
}

// One block = one batch (blk>>6) x one group of 64 src points (blk&63).
// Thread layout: s_local = tid>>2 (src in group), c = tid&3 (m-chunk of 1024).
__global__ __launch_bounds__(256) void nn_reduce(const float* __restrict__ src0,
                                                 float* __restrict__ S,
                                                 const float4* __restrict__ tgt4,
                                                 float* __restrict__ partials,
                                                 const float* __restrict__ Rt,
                                                 int apply) {
    __shared__ float4 T[MP];                      // 64 KB exactly

    const int b    = blockIdx.x >> 6;
    const int sblk = blockIdx.x & 63;
    const int tid  = threadIdx.x;
    const int s_local = tid >> 2;
    const int c       = tid & 3;
    const int n    = sblk * 64 + s_local;
    const int gsrc = b * NP + n;

    // Load src point; apply previous iteration's (R,t) if requested.
    float px, py, pz;
    if (apply) {
        float x = S[gsrc * 3 + 0];
        float y = S[gsrc * 3 + 1];
        float z = S[gsrc * 3 + 2];
        const float* Rb = Rt + b * 9;
        const float* tb = Rt + 36 + b * 3;
        // transformed = x @ R + t  (right-multiply, per reference)
        px = x * Rb[0] + y * Rb[3] + z * Rb[6] + tb[0];
        py = x * Rb[1] + y * Rb[4] + z * Rb[7] + tb[1];
        pz = x * Rb[2] + y * Rb[5] + z * Rb[8] + tb[2];
    } else {
        px = src0[gsrc * 3 + 0];
        py = src0[gsrc * 3 + 1];
        pz = src0[gsrc * 3 + 2];
    }

    // Stage this batch's tgt cloud into LDS (coalesced float4 loads).
    const float4* tg = tgt4 + b * MP;
    for (int j = tid; j < MP; j += 256) T[j] = tg[j];
    __syncthreads();

    // Persist transformed src for next iteration (reads happened pre-barrier).
    if (c == 0) {
        S[gsrc * 3 + 0] = px;
        S[gsrc * 3 + 1] = py;
        S[gsrc * 3 + 2] = pz;
    }

    // Scan m-chunk. d = |t|^2 - 2*s.t  (same ordering as xx+inner+yy; xx is a
    // per-src constant so argmin is unchanged). Strict < keeps first min.
    const float nx = -2.0f * px, ny = -2.0f * py, nz = -2.0f * pz;
    const int m0 = c << 10;
    float dmin = INFINITY;
    int   mmin = m0;
    #pragma unroll 4
    for (int mm = 0; mm < 1024; ++mm) {
        const int m = m0 + mm;
        float4 t = T[m];
        float d = fmaf(nx, t.x, fmaf(ny, t.y, fmaf(nz, t.z, t.w)));
        bool lt = d < dmin;
        dmin = lt ? d : dmin;
        mmin = lt ? m : mmin;
    }

    // Combine the 4 m-chunks (lanes s*4+c) with index tiebreak (first-min).
    {
        float d2 = __shfl_down(dmin, 1);
        int   i2 = __shfl_down(mmin, 1);
        if (d2 < dmin || (d2 == dmin && i2 < mmin)) { dmin = d2; mmin = i2; }
        d2 = __shfl_down(dmin, 2);
        i2 = __shfl_down(mmin, 2);
        if (d2 < dmin || (d2 == dmin && i2 < mmin)) { dmin = d2; mmin = i2; }
    }

    // Owner lanes (c==0) hold the matched index for their src point.
    const bool owner = (c == 0);
    float4 mt = T[mmin];
    const float sel = owner ? 1.0f : 0.0f;
    const float sx = px * sel, sy = py * sel, sz = pz * sel;
    const float tx = mt.x * sel, ty = mt.y * sel, tz = mt.z * sel;

    float v[15];
    v[0]  = sx;      v[1]  = sy;      v[2]  = sz;
    v[3]  = tx;      v[4]  = ty;      v[5]  = tz;
    v[6]  = sx * tx; v[7]  = sx * ty; v[8]  = sx * tz;
    v[9]  = sy * tx; v[10] = sy * ty; v[11] = sy * tz;
    v[12] = sz * tx; v[13] = sz * ty; v[14] = sz * tz;

    // Wave-wide sum (non-owners contribute 0).
    #pragma unroll
    for (int k = 0; k < 15; ++k) {
        float s = v[k];
        s += __shfl_down(s, 32);
        s += __shfl_down(s, 16);
        s += __shfl_down(s, 8);
        s += __shfl_down(s, 4);
        s += __shfl_down(s, 2);
        s += __shfl_down(s, 1);
        v[k] = s;
    }
    if ((tid & 63) == 0) {
        float* pp = partials + (blockIdx.x * 4 + (tid >> 6)) * 16;
        #pragma unroll
        for (int k = 0; k < 15; ++k) pp[k] = v[k];
    }
}

// One block of 64 threads. Threads (b = tid>>4, part = tid&15) sum partial
// rows deterministically; lane part==0 of each group does the 3x3 Kabsch.
__global__ __launch_bounds__(64) void solve_rt(const float* __restrict__ partials,
                                               float* __restrict__ Rt) {
    const int tid  = threadIdx.x;
    const int b    = tid >> 4;
    const int part = tid & 15;

    double s[15];
    #pragma unroll
    for (int k = 0; k < 15; ++k) s[k] = 0.0;
    const float* base = partials + (b * 256 + part * 16) * 16;
    for (int r = 0; r < 16; ++r) {
        #pragma unroll
        for (int k = 0; k < 15; ++k) s[k] += (double)base[r * 16 + k];
    }
    #pragma unroll
    for (int k = 0; k < 15; ++k) {
        double v = s[k];
        v += __shfl_down(v, 8);
        v += __shfl_down(v, 4);
        v += __shfl_down(v, 2);
        v += __shfl_down(v, 1);
        s[k] = v;
    }
    if (part != 0) return;

    const double invN = 1.0 / (double)NP;
    double cs[3] = { s[0] * invN, s[1] * invN, s[2] * invN };
    double ct[3] = { s[3] * invN, s[4] * invN, s[5] * invN };
    double H[3][3];
    for (int d = 0; d < 3; ++d)
        for (int e = 0; e < 3; ++e)
            H[d][e] = s[6 + d * 3 + e] * invN - cs[d] * ct[e];

    // A = H^T H (symmetric), Jacobi eigendecomposition -> V, lam.
    double A[3][3];
    for (int i = 0; i < 3; ++i)
        for (int j = 0; j < 3; ++j)
            A[i][j] = H[0][i] * H[0][j] + H[1][i] * H[1][j] + H[2][i] * H[2][j];

    double V[3][3] = {{1, 0, 0}, {0, 1, 0}, {0, 0, 1}};
    for (int sweep = 0; sweep < 20; ++sweep) {
        double off = A[0][1] * A[0][1] + A[0][2] * A[0][2] + A[1][2] * A[1][2];
        if (off < 1e-40) break;
        for (int pi = 0; pi < 3; ++pi) {
            const int p = (pi == 2) ? 1 : 0;
            const int q = (pi == 0) ? 1 : 2;
            double apq = A[p][q];
            if (apq == 0.0) continue;
            double theta = (A[q][q] - A[p][p]) / (2.0 * apq);
            double t = 1.0 / (fabs(theta) + sqrt(1.0 + theta * theta));
            if (theta < 0.0) t = -t;
            double cth = 1.0 / sqrt(1.0 + t * t);
            double sth = t * cth;
            double App = A[p][p], Aqq = A[q][q];
            A[p][p] = App - t * apq;
            A[q][q] = Aqq + t * apq;
            A[p][q] = A[q][p] = 0.0;
            const int r = 3 - p - q;
            double Apr = A[p][r], Aqr = A[q][r];
            A[p][r] = A[r][p] = cth * Apr - sth * Aqr;
            A[q][r] = A[r][q] = sth * Apr + cth * Aqr;
            for (int i = 0; i < 3; ++i) {
                double Vip = V[i][p], Viq = V[i][q];
                V[i][p] = cth * Vip - sth * Viq;
                V[i][q] = sth * Vip + cth * Viq;
            }
        }
    }
    double lam[3] = { A[0][0], A[1][1], A[2][2] };
    for (int i = 0; i < 2; ++i)
        for (int j = i + 1; j < 3; ++j)
            if (lam[j] > lam[i]) {
                double tl = lam[i]; lam[i] = lam[j]; lam[j] = tl;
                for (int k = 0; k < 3; ++k) {
                    double tv = V[k][i]; V[k][i] = V[k][j]; V[k][j] = tv;
                }
            }

    // U columns: u_k = H v_k / |H v_k|  (k sorted by descending sigma).
    double U[3][3];
    for (int k = 0; k < 3; ++k) {
        double w0 = H[0][0] * V[0][k] + H[0][1] * V[1][k] + H[0][2] * V[2][k];
        double w1 = H[1][0] * V[0][k] + H[1][1] * V[1][k] + H[1][2] * V[2][k];
        double w2 = H[2][0] * V[0][k] + H[2][1] * V[1][k] + H[2][2] * V[2][k];
        double nrm = sqrt(w0 * w0 + w1 * w1 + w2 * w2);
        if (nrm > 1e-150) {
            U[0][k] = w0 / nrm; U[1][k] = w1 / nrm; U[2][k] = w2 / nrm;
        } else {
            // degenerate sigma_3: u3 = u1 x u2 (sign handled by det fix)
            U[0][k] = U[1][0] * U[2][1] - U[2][0] * U[1][1];
            U[1][k] = U[2][0] * U[0][1] - U[0][0] * U[2][1];
            U[2][k] = U[0][0] * U[1][1] - U[1][0] * U[0][1];
        }
    }

    double detH = H[0][0] * (H[1][1] * H[2][2] - H[1][2] * H[2][1])
                - H[0][1] * (H[1][0] * H[2][2] - H[1][2] * H[2][0])
                + H[0][2] * (H[1][0] * H[2][1] - H[1][1] * H[2][0]);
    double sgn = (detH < 0.0) ? -1.0 : 1.0;

    // R = [v1 v2 s*v3] @ U^T  — the Kabsch optimum (unique; matches reference).
    double R[3][3];
    for (int i = 0; i < 3; ++i)
        for (int j = 0; j < 3; ++j)
            R[i][j] = V[i][0] * U[j][0] + V[i][1] * U[j][1] + sgn * V[i][2] * U[j][2];
    double t[3];
    for (int i = 0; i < 3; ++i)
        t[i] = ct[i] - (R[i][0] * cs[0] + R[i][1] * cs[1] + R[i][2] * cs[2]);

    for (int i = 0; i < 3; ++i)
        for (int j = 0; j < 3; ++j)
            Rt[b * 9 + i * 3 + j] = (float)R[i][j];
    for (int i = 0; i < 3; ++i)
        Rt[36 + b * 3 + i] = (float)t[i];
}

__global__ __launch_bounds__(256) void finalize(const float* __restrict__ S,
                                                const float* __restrict__ Rt,
                                                float* __restrict__ out) {
    const int gid = blockIdx.x * 256 + threadIdx.x;   // 0..16383
    const int b = gid >> 12;
    float x = S[gid * 3 + 0];
    float y = S[gid * 3 + 1];
    float z = S[gid * 3 + 2];
    const float* Rb = Rt + b * 9;
    const float* tb = Rt + 36 + b * 3;
    float qx = x * Rb[0] + y * Rb[3] + z * Rb[6] + tb[0];
    float qy = x * Rb[1] + y * Rb[4] + z * Rb[7] + tb[1];
    float qz = x * Rb[2] + y * Rb[5] + z * Rb[8] + tb[2];
    out[48 + gid * 3 + 0] = qx;
    out[48 + gid * 3 + 1] = qy;
    out[48 + gid * 3 + 2] = qz;
    if (blockIdx.x == 0 && threadIdx.x < 48)
        out[threadIdx.x] = Rt[threadIdx.x];   // R flat [4,3,3], then t flat [4,3]
}

extern "C" void kernel_launch(void* const* d_in, const int* in_sizes, int n_in,
                              void* d_out, int out_size, void* d_ws, size_t ws_size,
                              hipStream_t stream) {
    const float* src = (const float*)d_in[0];
    const float* tgt = (const float*)d_in[1];
    float* out = (float*)d_out;

    float* W        = (float*)d_ws;
    float4* tgt4    = (float4*)W;             // 65536 floats
    float* S        = W + 65536;              // 49152 floats
    float* partials = W + 65536 + 49152;      // 16384 floats
    float* Rt       = partials + 16384;       // 48 floats

    init_tgt<<<64, 256, 0, stream>>>(tgt, tgt4);
    for (int i = 0; i < 10; ++i) {
        nn_reduce<<<NB * 64, 256, 0, stream>>>(src, S, tgt4, partials, Rt, i > 0 ? 1 : 0);
        solve_rt<<<1, 64, 0, stream>>>(partials, Rt);
    }
    finalize<<<64, 256, 0, stream>>>(S, Rt, out);
}

// Round 2
// 417.234 us; speedup vs baseline: 1.1504x; 1.1504x over previous
//
#include <hip/hip_runtime.h>
#include <math.h>

#define NB 4
#define NP 4096   // src points per batch
#define MP 4096   // tgt points per batch

// ---------------------------------------------------------------------------
// Workspace layout (floats):
//   tgt4     : [0,      65536)   NB*MP float4 (x,y,z,|t|^2)
//   S        : [65536, 114688)   NB*NP*3 current transformed src
//   partials : [114688,118784)   256 rows x 16 floats (one per block)
//   Rt       : [118784,118832)   R[4][3][3] flat (36) + t[4][3] flat (12)
// ---------------------------------------------------------------------------

__global__ __launch_bounds__(256) void init_tgt(const float* __restrict__ tgt,
                                                float4* __restrict__ tgt4) {
    int j = blockIdx.x * 256 + threadIdx.x;       // 0..16383
    float x = tgt[j * 3 + 0];
    float y = tgt[j * 3 + 1];
    float z = tgt[j * 3 + 2];
    tgt4[j] = make_float4(x, y, z, x * x + y * y + z * z);
}

// One block = one batch (blk>>6) x one group of 64 src points (blk&63).
// All 4 waves own the SAME 64 src points (lane l -> src l of the group);
// wave w scans tgt chunk [w*1024, w*1024+1024) with BROADCAST LDS reads
// (all 64 lanes read the same address -> free, 16 B per instruction).
// Running argmin is a packed u32 key: top 20 bits = quantized distance
// (biased so it's strictly positive -> uint order == float order), low 12
// bits = tgt index. min_u32 keeps first-min on quantized ties.
__global__ __launch_bounds__(256) void nn_reduce(const float* __restrict__ src0,
                                                 float* __restrict__ S,
                                                 const float4* __restrict__ tgt4,
                                                 float* __restrict__ partials,
                                                 const float* __restrict__ Rt,
                                                 int apply) {
    __shared__ float4 T[MP];                      // 64 KB exactly

    const int b   = blockIdx.x >> 6;
    const int g   = blockIdx.x & 63;
    const int tid = threadIdx.x;
    const int w   = tid >> 6;
    const int l   = tid & 63;
    const int gsrc = b * NP + g * 64 + l;

    // Load src point; apply previous iteration's (R,t) if requested.
    float px, py, pz;
    if (apply) {
        float x = S[gsrc * 3 + 0];
        float y = S[gsrc * 3 + 1];
        float z = S[gsrc * 3 + 2];
        const float* Rb = Rt + b * 9;
        const float* tb = Rt + 36 + b * 3;
        // transformed = x @ R + t  (right-multiply, per reference)
        px = x * Rb[0] + y * Rb[3] + z * Rb[6] + tb[0];
        py = x * Rb[1] + y * Rb[4] + z * Rb[7] + tb[1];
        pz = x * Rb[2] + y * Rb[5] + z * Rb[8] + tb[2];
    } else {
        px = src0[gsrc * 3 + 0];
        py = src0[gsrc * 3 + 1];
        pz = src0[gsrc * 3 + 2];
    }

    // Stage this batch's tgt cloud into LDS (coalesced float4 loads).
    const float4* tg = tgt4 + b * MP;
    for (int j = tid; j < MP; j += 256) T[j] = tg[j];
    __syncthreads();

    // Persist transformed src for next iteration (wave 0 owns the write).
    if (tid < 64) {
        S[gsrc * 3 + 0] = px;
        S[gsrc * 3 + 1] = py;
        S[gsrc * 3 + 2] = pz;
    }

    // d = |s|^2 - 2 s.t + |t|^2 + 1  (>= ~1, so fp rounding can't make it
    // negative and positive-float bit pattern is monotone for u32 compare).
    const float nx = -2.0f * px, ny = -2.0f * py, nz = -2.0f * pz;
    const float sxx = px * px + py * py + pz * pz + 1.0f;
    const int m0 = w << 10;
    unsigned int best = 0xFFFFFFFFu;
    #pragma unroll 8
    for (int mm = 0; mm < 1024; ++mm) {
        float4 t = T[m0 + mm];                    // broadcast read
        float d = fmaf(nx, t.x, fmaf(ny, t.y, fmaf(nz, t.z, t.w + sxx)));
        unsigned int key = (__float_as_uint(d) & 0xFFFFF000u) |
                           (unsigned int)(m0 + mm);
        best = best < key ? best : key;
    }

    // Gather this wave's candidate matched point BEFORE repurposing T.
    float4 mt = T[best & 0xFFFu];
    __syncthreads();

    // Repurpose T[0..255] as the cross-wave combine area.
    ((float4*)T)[w * 64 + l] = make_float4(mt.x, mt.y, mt.z,
                                           __uint_as_float(best));
    __syncthreads();

    if (w == 0) {
        float4 r0 = T[l], r1 = T[64 + l], r2 = T[128 + l], r3 = T[192 + l];
        unsigned int k0 = __float_as_uint(r0.w);
        unsigned int k1 = __float_as_uint(r1.w);
        unsigned int k2 = __float_as_uint(r2.w);
        unsigned int k3 = __float_as_uint(r3.w);
        float4 mbest = r0; unsigned int kbest = k0;
        if (k1 < kbest) { kbest = k1; mbest = r1; }
        if (k2 < kbest) { kbest = k2; mbest = r2; }
        if (k3 < kbest) { kbest = k3; mbest = r3; }
        const float tx = mbest.x, ty = mbest.y, tz = mbest.z;

        float v[15];
        v[0]  = px;      v[1]  = py;      v[2]  = pz;
        v[3]  = tx;      v[4]  = ty;      v[5]  = tz;
        v[6]  = px * tx; v[7]  = px * ty; v[8]  = px * tz;
        v[9]  = py * tx; v[10] = py * ty; v[11] = py * tz;
        v[12] = pz * tx; v[13] = pz * ty; v[14] = pz * tz;

        #pragma unroll
        for (int k = 0; k < 15; ++k) {
            float s = v[k];
            s += __shfl_down(s, 32);
            s += __shfl_down(s, 16);
            s += __shfl_down(s, 8);
            s += __shfl_down(s, 4);
            s += __shfl_down(s, 2);
            s += __shfl_down(s, 1);
            v[k] = s;
        }
        if (l == 0) {
            float* pp = partials + blockIdx.x * 16;
            #pragma unroll
            for (int k = 0; k < 15; ++k) pp[k] = v[k];
        }
    }
}

// One block of 64 threads. Threads (b = tid>>4, part = tid&15) sum partial
// rows deterministically; lane part==0 of each group does the 3x3 Kabsch.
__global__ __launch_bounds__(64) void solve_rt(const float* __restrict__ partials,
                                               float* __restrict__ Rt) {
    const int tid  = threadIdx.x;
    const int b    = tid >> 4;
    const int part = tid & 15;

    double s[15];
    #pragma unroll
    for (int k = 0; k < 15; ++k) s[k] = 0.0;
    const float* base = partials + (b * 64 + part * 4) * 16;
    for (int r = 0; r < 4; ++r) {
        #pragma unroll
        for (int k = 0; k < 15; ++k) s[k] += (double)base[r * 16 + k];
    }
    #pragma unroll
    for (int k = 0; k < 15; ++k) {
        double v = s[k];
        v += __shfl_down(v, 8);
        v += __shfl_down(v, 4);
        v += __shfl_down(v, 2);
        v += __shfl_down(v, 1);
        s[k] = v;
    }
    if (part != 0) return;

    const double invN = 1.0 / (double)NP;
    double cs[3] = { s[0] * invN, s[1] * invN, s[2] * invN };
    double ct[3] = { s[3] * invN, s[4] * invN, s[5] * invN };
    double H[3][3];
    for (int d = 0; d < 3; ++d)
        for (int e = 0; e < 3; ++e)
            H[d][e] = s[6 + d * 3 + e] * invN - cs[d] * ct[e];

    // A = H^T H (symmetric), Jacobi eigendecomposition -> V, lam.
    double A[3][3];
    for (int i = 0; i < 3; ++i)
        for (int j = 0; j < 3; ++j)
            A[i][j] = H[0][i] * H[0][j] + H[1][i] * H[1][j] + H[2][i] * H[2][j];

    double V[3][3] = {{1, 0, 0}, {0, 1, 0}, {0, 0, 1}};
    for (int sweep = 0; sweep < 20; ++sweep) {
        double off = A[0][1] * A[0][1] + A[0][2] * A[0][2] + A[1][2] * A[1][2];
        if (off < 1e-40) break;
        for (int pi = 0; pi < 3; ++pi) {
            const int p = (pi == 2) ? 1 : 0;
            const int q = (pi == 0) ? 1 : 2;
            double apq = A[p][q];
            if (apq == 0.0) continue;
            double theta = (A[q][q] - A[p][p]) / (2.0 * apq);
            double t = 1.0 / (fabs(theta) + sqrt(1.0 + theta * theta));
            if (theta < 0.0) t = -t;
            double cth = 1.0 / sqrt(1.0 + t * t);
            double sth = t * cth;
            double App = A[p][p], Aqq = A[q][q];
            A[p][p] = App - t * apq;
            A[q][q] = Aqq + t * apq;
            A[p][q] = A[q][p] = 0.0;
            const int r = 3 - p - q;
            double Apr = A[p][r], Aqr = A[q][r];
            A[p][r] = A[r][p] = cth * Apr - sth * Aqr;
            A[q][r] = A[r][q] = sth * Apr + cth * Aqr;
            for (int i = 0; i < 3; ++i) {
                double Vip = V[i][p], Viq = V[i][q];
                V[i][p] = cth * Vip - sth * Viq;
                V[i][q] = sth * Vip + cth * Viq;
            }
        }
    }
    double lam[3] = { A[0][0], A[1][1], A[2][2] };
    for (int i = 0; i < 2; ++i)
        for (int j = i + 1; j < 3; ++j)
            if (lam[j] > lam[i]) {
                double tl = lam[i]; lam[i] = lam[j]; lam[j] = tl;
                for (int k = 0; k < 3; ++k) {
                    double tv = V[k][i]; V[k][i] = V[k][j]; V[k][j] = tv;
                }
            }

    // U columns: u_k = H v_k / |H v_k|  (k sorted by descending sigma).
    double U[3][3];
    for (int k = 0; k < 3; ++k) {
        double w0 = H[0][0] * V[0][k] + H[0][1] * V[1][k] + H[0][2] * V[2][k];
        double w1 = H[1][0] * V[0][k] + H[1][1] * V[1][k] + H[1][2] * V[2][k];
        double w2 = H[2][0] * V[0][k] + H[2][1] * V[1][k] + H[2][2] * V[2][k];
        double nrm = sqrt(w0 * w0 + w1 * w1 + w2 * w2);
        if (nrm > 1e-150) {
            U[0][k] = w0 / nrm; U[1][k] = w1 / nrm; U[2][k] = w2 / nrm;
        } else {
            // degenerate sigma_3: u3 = u1 x u2 (sign handled by det fix)
            U[0][k] = U[1][0] * U[2][1] - U[2][0] * U[1][1];
            U[1][k] = U[2][0] * U[0][1] - U[0][0] * U[2][1];
            U[2][k] = U[0][0] * U[1][1] - U[1][0] * U[0][1];
        }
    }

    double detH = H[0][0] * (H[1][1] * H[2][2] - H[1][2] * H[2][1])
                - H[0][1] * (H[1][0] * H[2][2] - H[1][2] * H[2][0])
                + H[0][2] * (H[1][0] * H[2][1] - H[1][1] * H[2][0]);
    double sgn = (detH < 0.0) ? -1.0 : 1.0;

    // R = [v1 v2 s*v3] @ U^T  — the Kabsch optimum (unique; matches reference).
    double R[3][3];
    for (int i = 0; i < 3; ++i)
        for (int j = 0; j < 3; ++j)
            R[i][j] = V[i][0] * U[j][0] + V[i][1] * U[j][1] + sgn * V[i][2] * U[j][2];
    double t[3];
    for (int i = 0; i < 3; ++i)
        t[i] = ct[i] - (R[i][0] * cs[0] + R[i][1] * cs[1] + R[i][2] * cs[2]);

    for (int i = 0; i < 3; ++i)
        for (int j = 0; j < 3; ++j)
            Rt[b * 9 + i * 3 + j] = (float)R[i][j];
    for (int i = 0; i < 3; ++i)
        Rt[36 + b * 3 + i] = (float)t[i];
}

__global__ __launch_bounds__(256) void finalize(const float* __restrict__ S,
                                                const float* __restrict__ Rt,
                                                float* __restrict__ out) {
    const int gid = blockIdx.x * 256 + threadIdx.x;   // 0..16383
    const int b = gid >> 12;
    float x = S[gid * 3 + 0];
    float y = S[gid * 3 + 1];
    float z = S[gid * 3 + 2];
    const float* Rb = Rt + b * 9;
    const float* tb = Rt + 36 + b * 3;
    float qx = x * Rb[0] + y * Rb[3] + z * Rb[6] + tb[0];
    float qy = x * Rb[1] + y * Rb[4] + z * Rb[7] + tb[1];
    float qz = x * Rb[2] + y * Rb[5] + z * Rb[8] + tb[2];
    out[48 + gid * 3 + 0] = qx;
    out[48 + gid * 3 + 1] = qy;
    out[48 + gid * 3 + 2] = qz;
    if (blockIdx.x == 0 && threadIdx.x < 48)
        out[threadIdx.x] = Rt[threadIdx.x];   // R flat [4,3,3], then t flat [4,3]
}

extern "C" void kernel_launch(void* const* d_in, const int* in_sizes, int n_in,
                              void* d_out, int out_size, void* d_ws, size_t ws_size,
                              hipStream_t stream) {
    const float* src = (const float*)d_in[0];
    const float* tgt = (const float*)d_in[1];
    float* out = (float*)d_out;

    float* W        = (float*)d_ws;
    float4* tgt4    = (float4*)W;             // 65536 floats
    float* S        = W + 65536;              // 49152 floats
    float* partials = W + 65536 + 49152;      // 4096 floats (256 rows x 16)
    float* Rt       = partials + 4096;        // 48 floats

    init_tgt<<<64, 256, 0, stream>>>(tgt, tgt4);
    for (int i = 0; i < 10; ++i) {
        nn_reduce<<<NB * 64, 256, 0, stream>>>(src, S, tgt4, partials, Rt, i > 0 ? 1 : 0);
        solve_rt<<<1, 64, 0, stream>>>(partials, Rt);
    }
    finalize<<<64, 256, 0, stream>>>(S, Rt, out);
}